// Round 7
// baseline (1674.770 us; speedup 1.0000x reference)
//
#include <hip/hip_runtime.h>
#include <hip/hip_bf16.h>
#include <stdint.h>

#define N_NODES 50000
#define F_IN 256
#define HID 128
#define NH 8
#define DH 16
#define NE 800000
#define NM 3
#define NOUT 8
#define NEG 0.2f
#define NROWS (N_NODES * NM)   // 150000 semantic rows
#define LDA 68                 // padded LDS stride for GEMM tiles
#define NBLK 196               // ceil(50000/256) scan blocks
#define BSH 6                  // bucket shift: 64 dst per bucket
#define NBUCK 782              // ceil(50000/64)

// ---------------- CSR build ----------------
__global__ __launch_bounds__(256) void k_hist(const int* __restrict__ dst,
                                              int* __restrict__ deg) {
    int e = blockIdx.x * 256 + threadIdx.x;
    int m = blockIdx.y;
    if (e >= NE) return;
    atomicAdd(&deg[m * N_NODES + dst[(size_t)m * NE + e]], 1);
}

// block-level exclusive scan: per-element prefix within block + block sums
__global__ __launch_bounds__(256) void k_scan1(const int* __restrict__ deg,
                                               int* __restrict__ pfx,
                                               int* __restrict__ blksum) {
    __shared__ int sc[256];
    int m = blockIdx.y, blk = blockIdx.x, t = threadIdx.x;
    int i = blk * 256 + t;
    int v = (i < N_NODES) ? deg[m * N_NODES + i] : 0;
    sc[t] = v;
    __syncthreads();
    #pragma unroll
    for (int o = 1; o < 256; o <<= 1) {
        int add = (t >= o) ? sc[t - o] : 0;
        __syncthreads();
        sc[t] += add;
        __syncthreads();
    }
    if (i < N_NODES) pfx[m * N_NODES + i] = sc[t] - v;
    if (t == 255) blksum[m * NBLK + blk] = sc[255];
}

// scan the 196 block sums per metapath
__global__ __launch_bounds__(256) void k_scan2(const int* __restrict__ blksum,
                                               int* __restrict__ blkbase) {
    __shared__ int sc[256];
    int m = blockIdx.x, t = threadIdx.x;
    int v = (t < NBLK) ? blksum[m * NBLK + t] : 0;
    sc[t] = v;
    __syncthreads();
    #pragma unroll
    for (int o = 1; o < 256; o <<= 1) {
        int add = (t >= o) ? sc[t - o] : 0;
        __syncthreads();
        sc[t] += add;
        __syncthreads();
    }
    if (t < NBLK) blkbase[m * NBLK + t] = sc[t] - v;
}

// offs = blkbase + pfx; init per-dst cursors and per-bucket cursors
__global__ __launch_bounds__(256) void k_scan3(const int* __restrict__ pfx,
                                               const int* __restrict__ blkbase,
                                               int* __restrict__ offs,
                                               int* __restrict__ dstCur,
                                               int* __restrict__ binCur) {
    int m = blockIdx.y, blk = blockIdx.x, t = threadIdx.x;
    int i = blk * 256 + t;
    if (i < N_NODES) {
        int o = blkbase[m * NBLK + blk] + pfx[m * N_NODES + i];
        offs[m * (N_NODES + 1) + i] = o;
        dstCur[m * N_NODES + i] = o;
        if ((i & ((1 << BSH) - 1)) == 0) binCur[m * NBUCK + (i >> BSH)] = o;
    }
    if (i == 0) offs[m * (N_NODES + 1) + N_NODES] = NE;
}

// phase A: bin (src,dst) pairs by dst>>BSH into bucket-partitioned regions
__global__ __launch_bounds__(256) void k_binA(const int* __restrict__ src,
                                              const int* __restrict__ dst,
                                              int* __restrict__ binCur,
                                              int2* __restrict__ pairs) {
    int e = blockIdx.x * 256 + threadIdx.x;
    if (e >= NE) return;
    int d = dst[e], s = src[e];
    int pos = atomicAdd(&binCur[d >> BSH], 1);
    pairs[pos] = make_int2(s, d);
}

// phase B: within-bucket scatter to final per-dst position (4KB windows, L2-hot)
__global__ __launch_bounds__(256) void k_binB(const int2* __restrict__ pairs,
                                              int* __restrict__ dstCur,
                                              int* __restrict__ ssrc) {
    int i = blockIdx.x * 256 + threadIdx.x;
    if (i >= NE) return;
    int2 p = pairs[i];
    int pos = atomicAdd(&dstCur[p.y], 1);
    ssrc[pos] = p.x;
}

// ---------------- K1: h = feat @ W_fc + b (LDS-tiled, 64 rows/block) ----------
__global__ __launch_bounds__(256) void k_fc(const float* __restrict__ A,
                                            const float* __restrict__ B,
                                            const float* __restrict__ bias,
                                            float* __restrict__ C) {
    __shared__ float As[128 * LDA];
    int tid = threadIdx.x;
    int tc = tid & 15, tr = tid >> 4;
    int r0 = blockIdx.x * 64;
    int j0 = tc * 8;
    int rowA = tid & 63;
    int kc = tid >> 6;
    float acc[4][8];
    #pragma unroll
    for (int i = 0; i < 4; i++)
        #pragma unroll
        for (int c = 0; c < 8; c++) acc[i][c] = 0.f;

    int gr = r0 + rowA; if (gr > N_NODES - 1) gr = N_NODES - 1;
    for (int ph = 0; ph < 2; ph++) {
        __syncthreads();
        const float* ap = A + (size_t)gr * F_IN + ph * 128 + kc * 32;
        #pragma unroll
        for (int i = 0; i < 8; i++) {
            float4 v = ((const float4*)ap)[i];
            int k = kc * 32 + i * 4;
            As[(k + 0) * LDA + rowA] = v.x;
            As[(k + 1) * LDA + rowA] = v.y;
            As[(k + 2) * LDA + rowA] = v.z;
            As[(k + 3) * LDA + rowA] = v.w;
        }
        __syncthreads();
        const float* bp = B + (size_t)(ph * 128) * HID + j0;
        #pragma unroll 4
        for (int k = 0; k < 128; k++) {
            float4 a4 = *(const float4*)&As[k * LDA + tr * 4];
            float4 b0 = *(const float4*)&bp[(size_t)k * HID];
            float4 b1 = *(const float4*)&bp[(size_t)k * HID + 4];
            float av[4] = {a4.x, a4.y, a4.z, a4.w};
            float bv[8] = {b0.x, b0.y, b0.z, b0.w, b1.x, b1.y, b1.z, b1.w};
            #pragma unroll
            for (int i = 0; i < 4; i++)
                #pragma unroll
                for (int c = 0; c < 8; c++) acc[i][c] += av[i] * bv[c];
        }
    }
    float bb[8];
    #pragma unroll
    for (int c = 0; c < 8; c++) bb[c] = bias[j0 + c];
    #pragma unroll
    for (int i = 0; i < 4; i++) {
        int row = r0 + tr * 4 + i;
        if (row < N_NODES) {
            float4 o0 = {acc[i][0] + bb[0], acc[i][1] + bb[1], acc[i][2] + bb[2], acc[i][3] + bb[3]};
            float4 o1 = {acc[i][4] + bb[4], acc[i][5] + bb[5], acc[i][6] + bb[6], acc[i][7] + bb[7]};
            *(float4*)&C[(size_t)row * HID + j0] = o0;
            *(float4*)&C[(size_t)row * HID + j0 + 4] = o1;
        }
    }
}

// ------- K2: fs = h@Wsrc (stored), fd = h@Wdst (el/er only, not stored) -------
__global__ __launch_bounds__(256) void k_proj(const float* __restrict__ A,
                                              const float* __restrict__ Bs,
                                              const float* __restrict__ Bd,
                                              const float* __restrict__ al,
                                              const float* __restrict__ ar,
                                              float* __restrict__ fs,
                                              float* __restrict__ el,
                                              float* __restrict__ er) {
    __shared__ float As[128 * LDA];
    int tid = threadIdx.x;
    int tc = tid & 15, tr = tid >> 4;
    int r0 = blockIdx.x * 64;
    int j0 = tc * 8;
    int rowA = tid & 63;
    int kc = tid >> 6;
    float as_[4][8], ad_[4][8];
    #pragma unroll
    for (int i = 0; i < 4; i++)
        #pragma unroll
        for (int c = 0; c < 8; c++) { as_[i][c] = 0.f; ad_[i][c] = 0.f; }

    int gr = r0 + rowA; if (gr > N_NODES - 1) gr = N_NODES - 1;
    const float* ap = A + (size_t)gr * HID + kc * 32;
    #pragma unroll
    for (int i = 0; i < 8; i++) {
        float4 v = ((const float4*)ap)[i];
        int k = kc * 32 + i * 4;
        As[(k + 0) * LDA + rowA] = v.x;
        As[(k + 1) * LDA + rowA] = v.y;
        As[(k + 2) * LDA + rowA] = v.z;
        As[(k + 3) * LDA + rowA] = v.w;
    }
    __syncthreads();
    const float* bps = Bs + j0;
    const float* bpd = Bd + j0;
    #pragma unroll 2
    for (int k = 0; k < 128; k++) {
        float4 a4 = *(const float4*)&As[k * LDA + tr * 4];
        float4 s0 = *(const float4*)&bps[(size_t)k * HID];
        float4 s1 = *(const float4*)&bps[(size_t)k * HID + 4];
        float4 d0 = *(const float4*)&bpd[(size_t)k * HID];
        float4 d1 = *(const float4*)&bpd[(size_t)k * HID + 4];
        float av[4] = {a4.x, a4.y, a4.z, a4.w};
        float sv[8] = {s0.x, s0.y, s0.z, s0.w, s1.x, s1.y, s1.z, s1.w};
        float dv[8] = {d0.x, d0.y, d0.z, d0.w, d1.x, d1.y, d1.z, d1.w};
        #pragma unroll
        for (int i = 0; i < 4; i++)
            #pragma unroll
            for (int c = 0; c < 8; c++) {
                as_[i][c] += av[i] * sv[c];
                ad_[i][c] += av[i] * dv[c];
            }
    }
    float alv[8], arv[8];
    #pragma unroll
    for (int c = 0; c < 8; c++) { alv[c] = al[j0 + c]; arv[c] = ar[j0 + c]; }
    int head = tc >> 1;
    #pragma unroll
    for (int i = 0; i < 4; i++) {
        int row = r0 + tr * 4 + i;
        bool ok = (row < N_NODES);
        if (ok) {
            float4 o0 = {as_[i][0], as_[i][1], as_[i][2], as_[i][3]};
            float4 o1 = {as_[i][4], as_[i][5], as_[i][6], as_[i][7]};
            *(float4*)&fs[(size_t)row * HID + j0] = o0;
            *(float4*)&fs[(size_t)row * HID + j0 + 4] = o1;
        }
        float pl = 0.f, pr = 0.f;
        #pragma unroll
        for (int c = 0; c < 8; c++) { pl += as_[i][c] * alv[c]; pr += ad_[i][c] * arv[c]; }
        pl += __shfl_xor(pl, 1);
        pr += __shfl_xor(pr, 1);
        if (ok && (tc & 1) == 0) {
            el[row * NH + head] = pl;
            er[row * NH + head] = pr;
        }
    }
}

// ---------------- K3: per-dst GAT aggregation; stores ELU(z) ----------------
__global__ __launch_bounds__(128) void k_gat(const int* __restrict__ ssrc,
                                             const int* __restrict__ offs,
                                             const float* __restrict__ el,
                                             const float* __restrict__ er,
                                             const float* __restrict__ fs,
                                             float* __restrict__ z, int m) {
    __shared__ float lds_part[128];
    __shared__ float inv_sum[NH];
    int d = blockIdx.x;
    int j = threadIdx.x;
    int s0 = offs[d], s1 = offs[d + 1];
    int t = j >> 3, hh2 = j & 7;
    float erd2 = er[d * NH + hh2];
    float part = 0.f;
    for (int i = s0 + t; i < s1; i += 16) {
        int s = ssrc[i];
        float x = el[s * NH + hh2] + erd2;
        x = (x >= 0.f) ? x : NEG * x;
        part += __expf(x);
    }
    lds_part[j] = part;
    __syncthreads();
    if (j < NH) {
        float acc = 0.f;
        #pragma unroll
        for (int t2 = 0; t2 < 16; t2++) acc += lds_part[t2 * 8 + j];
        inv_sum[j] = 1.f / fmaxf(acc, 1e-9f);
    }
    __syncthreads();
    int hh = j >> 4;
    float erd = er[d * NH + hh];
    float inv = inv_sum[hh];
    float acc = 0.f;
    for (int i = s0; i < s1; i++) {
        int s = ssrc[i];
        float x = el[s * NH + hh] + erd;
        x = (x >= 0.f) ? x : NEG * x;
        float alpha = __expf(x) * inv;
        acc += fs[(size_t)s * HID + j] * alpha;
    }
    z[(size_t)(d * NM + m) * HID + j] = (acc > 0.f) ? acc : (__expf(acc) - 1.f);
}

// -------- K4: w[r] = tanh(zel@W1 + b1) @ w2  (LDS-tiled, 64 rows/block) -------
__global__ __launch_bounds__(256) void k_semw(const float* __restrict__ A,
                                              const float* __restrict__ B,
                                              const float* __restrict__ b1,
                                              const float* __restrict__ ws2,
                                              float* __restrict__ w) {
    __shared__ float As[128 * LDA];
    int tid = threadIdx.x;
    int tc = tid & 15, tr = tid >> 4;
    int r0 = blockIdx.x * 64;
    int j0 = tc * 8;
    int rowA = tid & 63;
    int kc = tid >> 6;
    float acc[4][8];
    #pragma unroll
    for (int i = 0; i < 4; i++)
        #pragma unroll
        for (int c = 0; c < 8; c++) acc[i][c] = 0.f;

    int gr = r0 + rowA; if (gr > NROWS - 1) gr = NROWS - 1;
    const float* ap = A + (size_t)gr * HID + kc * 32;
    #pragma unroll
    for (int i = 0; i < 8; i++) {
        float4 v = ((const float4*)ap)[i];
        int k = kc * 32 + i * 4;
        As[(k + 0) * LDA + rowA] = v.x;
        As[(k + 1) * LDA + rowA] = v.y;
        As[(k + 2) * LDA + rowA] = v.z;
        As[(k + 3) * LDA + rowA] = v.w;
    }
    __syncthreads();
    const float* bp = B + j0;
    #pragma unroll 4
    for (int k = 0; k < 128; k++) {
        float4 a4 = *(const float4*)&As[k * LDA + tr * 4];
        float4 b0 = *(const float4*)&bp[(size_t)k * HID];
        float4 b1v = *(const float4*)&bp[(size_t)k * HID + 4];
        float av[4] = {a4.x, a4.y, a4.z, a4.w};
        float bv[8] = {b0.x, b0.y, b0.z, b0.w, b1v.x, b1v.y, b1v.z, b1v.w};
        #pragma unroll
        for (int i = 0; i < 4; i++)
            #pragma unroll
            for (int c = 0; c < 8; c++) acc[i][c] += av[i] * bv[c];
    }
    float bb[8], s2[8];
    #pragma unroll
    for (int c = 0; c < 8; c++) { bb[c] = b1[j0 + c]; s2[c] = ws2[j0 + c]; }
    #pragma unroll
    for (int i = 0; i < 4; i++) {
        float v = 0.f;
        #pragma unroll
        for (int c = 0; c < 8; c++) v += tanhf(acc[i][c] + bb[c]) * s2[c];
        #pragma unroll
        for (int o = 8; o > 0; o >>= 1) v += __shfl_down(v, o, 16);
        int row = r0 + tr * 4 + i;
        if (tc == 0 && row < NROWS) w[row] = v;
    }
}

// ---------------- K5: beta softmax + fused + out ----------------
__global__ __launch_bounds__(256) void k_comb(const float* __restrict__ zel,
                                              const float* __restrict__ w,
                                              const float* __restrict__ Wout,
                                              const float* __restrict__ bout,
                                              float* __restrict__ out) {
    __shared__ float fusedL[2][HID];
    int half = threadIdx.x >> 7;
    int j = threadIdx.x & 127;
    int n = blockIdx.x * 2 + half;
    float w0 = w[n * NM + 0];
    float w1 = w[n * NM + 1];
    float w2 = w[n * NM + 2];
    float mx = fmaxf(w0, fmaxf(w1, w2));
    float e0 = __expf(w0 - mx);
    float e1 = __expf(w1 - mx);
    float e2 = __expf(w2 - mx);
    float inv = 1.f / (e0 + e1 + e2);
    size_t base = (size_t)n * NM * HID;
    float f = (e0 * zel[base + j] + e1 * zel[base + HID + j] + e2 * zel[base + 2 * HID + j]) * inv;
    fusedL[half][j] = f;
    __syncthreads();
    int c = j >> 4, t16 = j & 15;
    float p = 0.f;
    #pragma unroll
    for (int i = 0; i < 8; i++) {
        int jj = t16 + i * 16;
        p += fusedL[half][jj] * Wout[jj * NOUT + c];
    }
    #pragma unroll
    for (int o = 8; o > 0; o >>= 1) p += __shfl_down(p, o, 16);
    if (t16 == 0) out[n * NOUT + c] = p + bout[c];
}

extern "C" void kernel_launch(void* const* d_in, const int* in_sizes, int n_in,
                              void* d_out, int out_size, void* d_ws, size_t ws_size,
                              hipStream_t stream) {
    (void)in_sizes; (void)n_in; (void)out_size; (void)ws_size;
    const float* feat  = (const float*)d_in[0];
    const float* Wfc   = (const float*)d_in[1];
    const float* bfc   = (const float*)d_in[2];
    const float* Wsrc  = (const float*)d_in[3];
    const float* Wdst  = (const float*)d_in[4];
    const float* al    = (const float*)d_in[5];
    const float* ar    = (const float*)d_in[6];
    const float* Wsem1 = (const float*)d_in[7];
    const float* bsem1 = (const float*)d_in[8];
    const float* wsem2 = (const float*)d_in[9];
    const float* Wout  = (const float*)d_in[10];
    const float* bout  = (const float*)d_in[11];
    const int* srcI    = (const int*)d_in[12];
    const int* dstI    = (const int*)d_in[13];
    float* out = (float*)d_out;

    // fp32 section
    float* h    = (float*)d_ws;
    float* z    = h  + (size_t)N_NODES * HID;
    float* fs   = z  + (size_t)N_NODES * NM * HID;
    float* el   = fs + (size_t)N_NODES * HID;
    float* er   = el + (size_t)N_NODES * NH;
    float* wsc  = er + (size_t)N_NODES * NH;
    // int section
    int* deg    = (int*)(wsc + (size_t)NROWS);
    int* offs   = deg    + (size_t)NM * N_NODES;
    int* ssrc   = offs   + (size_t)NM * (N_NODES + 1);
    int* pfx    = ssrc   + (size_t)NM * NE;
    int* dstCur = pfx    + (size_t)NM * N_NODES;
    int* blksum = dstCur + (size_t)NM * N_NODES;
    int* blkbase= blksum + (size_t)NM * NBLK;
    int* binCur = blkbase+ (size_t)NM * NBLK;
    int2* pairs = (int2*)((((uintptr_t)(binCur + (size_t)NM * NBUCK)) + 15) & ~(uintptr_t)15);

    // ---- CSR build ----
    hipMemsetAsync(deg, 0, (size_t)NM * N_NODES * sizeof(int), stream);
    {
        dim3 ge((NE + 255) / 256, NM);
        dim3 gs(NBLK, NM);
        k_hist<<<ge, 256, 0, stream>>>(dstI, deg);
        k_scan1<<<gs, 256, 0, stream>>>(deg, pfx, blksum);
        k_scan2<<<NM, 256, 0, stream>>>(blksum, blkbase);
        k_scan3<<<gs, 256, 0, stream>>>(pfx, blkbase, offs, dstCur, binCur);
        for (int m = 0; m < NM; m++) {
            k_binA<<<(NE + 255) / 256, 256, 0, stream>>>(srcI + (size_t)m * NE,
                                                         dstI + (size_t)m * NE,
                                                         binCur + (size_t)m * NBUCK, pairs);
            k_binB<<<(NE + 255) / 256, 256, 0, stream>>>(pairs,
                                                         dstCur + (size_t)m * N_NODES,
                                                         ssrc + (size_t)m * NE);
        }
    }

    k_fc<<<(N_NODES + 63) / 64, 256, 0, stream>>>(feat, Wfc, bfc, h);

    for (int m = 0; m < NM; m++) {
        k_proj<<<(N_NODES + 63) / 64, 256, 0, stream>>>(h, Wsrc + (size_t)m * HID * HID,
                                                        Wdst + (size_t)m * HID * HID,
                                                        al + m * NH * DH, ar + m * NH * DH,
                                                        fs, el, er);
        k_gat<<<N_NODES, 128, 0, stream>>>(ssrc + (size_t)m * NE,
                                           offs + (size_t)m * (N_NODES + 1),
                                           el, er, fs, z, m);
    }

    k_semw<<<(NROWS + 63) / 64, 256, 0, stream>>>(z, Wsem1, bsem1, wsem2, wsc);
    k_comb<<<N_NODES / 2, 256, 0, stream>>>(z, wsc, Wout, bout, out);
}

// Round 8
// 1165.983 us; speedup vs baseline: 1.4364x; 1.4364x over previous
//
#include <hip/hip_runtime.h>
#include <hip/hip_bf16.h>
#include <stdint.h>

#define N_NODES 50000
#define F_IN 256
#define HID 128
#define NH 8
#define DH 16
#define NE 800000
#define NM 3
#define NOUT 8
#define NEG 0.2f
#define NROWS (N_NODES * NM)   // 150000 semantic rows
#define LDA 68                 // padded LDS stride for GEMM tiles
#define NBLK 196               // ceil(50000/256) scan blocks
#define BSH 8                  // bucket shift: 256 dst per bucket
#define NBUCK 196              // ceil(50000/256)
#define EPB 8192               // edges per binning block

// ---------------- CSR build ----------------
__global__ __launch_bounds__(256) void k_hist(const int* __restrict__ dst,
                                              int* __restrict__ deg) {
    int e = blockIdx.x * 256 + threadIdx.x;
    int m = blockIdx.y;
    if (e >= NE) return;
    atomicAdd(&deg[m * N_NODES + dst[(size_t)m * NE + e]], 1);
}

__global__ __launch_bounds__(256) void k_scan1(const int* __restrict__ deg,
                                               int* __restrict__ pfx,
                                               int* __restrict__ blksum) {
    __shared__ int sc[256];
    int m = blockIdx.y, blk = blockIdx.x, t = threadIdx.x;
    int i = blk * 256 + t;
    int v = (i < N_NODES) ? deg[m * N_NODES + i] : 0;
    sc[t] = v;
    __syncthreads();
    #pragma unroll
    for (int o = 1; o < 256; o <<= 1) {
        int add = (t >= o) ? sc[t - o] : 0;
        __syncthreads();
        sc[t] += add;
        __syncthreads();
    }
    if (i < N_NODES) pfx[m * N_NODES + i] = sc[t] - v;
    if (t == 255) blksum[m * NBLK + blk] = sc[255];
}

__global__ __launch_bounds__(256) void k_scan2(const int* __restrict__ blksum,
                                               int* __restrict__ blkbase) {
    __shared__ int sc[256];
    int m = blockIdx.x, t = threadIdx.x;
    int v = (t < NBLK) ? blksum[m * NBLK + t] : 0;
    sc[t] = v;
    __syncthreads();
    #pragma unroll
    for (int o = 1; o < 256; o <<= 1) {
        int add = (t >= o) ? sc[t - o] : 0;
        __syncthreads();
        sc[t] += add;
        __syncthreads();
    }
    if (t < NBLK) blkbase[m * NBLK + t] = sc[t] - v;
}

// offs = blkbase + pfx; init per-dst cursors and per-bucket cursors
__global__ __launch_bounds__(256) void k_scan3(const int* __restrict__ pfx,
                                               const int* __restrict__ blkbase,
                                               int* __restrict__ offs,
                                               int* __restrict__ dstCur,
                                               int* __restrict__ binCur) {
    int m = blockIdx.y, blk = blockIdx.x, t = threadIdx.x;
    int i = blk * 256 + t;
    if (i < N_NODES) {
        int o = blkbase[m * NBLK + blk] + pfx[m * N_NODES + i];
        offs[m * (N_NODES + 1) + i] = o;
        dstCur[m * N_NODES + i] = o;
        if ((i & 255) == 0) binCur[m * NBUCK + (i >> BSH)] = o;
    }
    if (i == 0) offs[m * (N_NODES + 1) + N_NODES] = NE;
}

// phase A: block-local count -> one reservation atomic per (block,bucket)
// -> dense pair writes. pairs coordinates == ssrc coordinates.
__global__ __launch_bounds__(256) void k_binA2(const int* __restrict__ src,
                                               const int* __restrict__ dst,
                                               int* __restrict__ binCur,
                                               int2* __restrict__ pairs) {
    __shared__ int cnt[NBUCK];
    __shared__ int base[NBUCK];
    int t = threadIdx.x;
    int e0 = blockIdx.x * EPB;
    int e1 = e0 + EPB; if (e1 > NE) e1 = NE;
    for (int i = t; i < NBUCK; i += 256) cnt[i] = 0;
    __syncthreads();
    for (int i = e0 + t; i < e1; i += 256)
        atomicAdd(&cnt[dst[i] >> BSH], 1);
    __syncthreads();
    for (int i = t; i < NBUCK; i += 256) {
        int c = cnt[i];
        base[i] = c ? atomicAdd(&binCur[i], c) : 0;
        cnt[i] = 0;
    }
    __syncthreads();
    for (int i = e0 + t; i < e1; i += 256) {
        int d = dst[i], s = src[i];
        int b = d >> BSH;
        int off = atomicAdd(&cnt[b], 1);
        pairs[base[b] + off] = make_int2(s, d);
    }
}

// phase B: within-bucket scatter (each block's window ~16KB, L2-resident)
__global__ __launch_bounds__(256) void k_binB(const int2* __restrict__ pairs,
                                              int* __restrict__ dstCur,
                                              int* __restrict__ ssrc) {
    int i = blockIdx.x * 256 + threadIdx.x;
    if (i >= NE) return;
    int2 p = pairs[i];
    int pos = atomicAdd(&dstCur[p.y], 1);
    ssrc[pos] = p.x;
}

// ---------------- K1: h = feat @ W_fc + b (LDS-tiled, 64 rows/block) ----------
__global__ __launch_bounds__(256) void k_fc(const float* __restrict__ A,
                                            const float* __restrict__ B,
                                            const float* __restrict__ bias,
                                            float* __restrict__ C) {
    __shared__ float As[128 * LDA];
    int tid = threadIdx.x;
    int tc = tid & 15, tr = tid >> 4;
    int r0 = blockIdx.x * 64;
    int j0 = tc * 8;
    int rowA = tid & 63;
    int kc = tid >> 6;
    float acc[4][8];
    #pragma unroll
    for (int i = 0; i < 4; i++)
        #pragma unroll
        for (int c = 0; c < 8; c++) acc[i][c] = 0.f;

    int gr = r0 + rowA; if (gr > N_NODES - 1) gr = N_NODES - 1;
    for (int ph = 0; ph < 2; ph++) {
        __syncthreads();
        const float* ap = A + (size_t)gr * F_IN + ph * 128 + kc * 32;
        #pragma unroll
        for (int i = 0; i < 8; i++) {
            float4 v = ((const float4*)ap)[i];
            int k = kc * 32 + i * 4;
            As[(k + 0) * LDA + rowA] = v.x;
            As[(k + 1) * LDA + rowA] = v.y;
            As[(k + 2) * LDA + rowA] = v.z;
            As[(k + 3) * LDA + rowA] = v.w;
        }
        __syncthreads();
        const float* bp = B + (size_t)(ph * 128) * HID + j0;
        #pragma unroll 4
        for (int k = 0; k < 128; k++) {
            float4 a4 = *(const float4*)&As[k * LDA + tr * 4];
            float4 b0 = *(const float4*)&bp[(size_t)k * HID];
            float4 b1 = *(const float4*)&bp[(size_t)k * HID + 4];
            float av[4] = {a4.x, a4.y, a4.z, a4.w};
            float bv[8] = {b0.x, b0.y, b0.z, b0.w, b1.x, b1.y, b1.z, b1.w};
            #pragma unroll
            for (int i = 0; i < 4; i++)
                #pragma unroll
                for (int c = 0; c < 8; c++) acc[i][c] += av[i] * bv[c];
        }
    }
    float bb[8];
    #pragma unroll
    for (int c = 0; c < 8; c++) bb[c] = bias[j0 + c];
    #pragma unroll
    for (int i = 0; i < 4; i++) {
        int row = r0 + tr * 4 + i;
        if (row < N_NODES) {
            float4 o0 = {acc[i][0] + bb[0], acc[i][1] + bb[1], acc[i][2] + bb[2], acc[i][3] + bb[3]};
            float4 o1 = {acc[i][4] + bb[4], acc[i][5] + bb[5], acc[i][6] + bb[6], acc[i][7] + bb[7]};
            *(float4*)&C[(size_t)row * HID + j0] = o0;
            *(float4*)&C[(size_t)row * HID + j0 + 4] = o1;
        }
    }
}

// ------- K2: fs = h@Wsrc (stored), fd = h@Wdst (el/er only, not stored) -------
__global__ __launch_bounds__(256) void k_proj(const float* __restrict__ A,
                                              const float* __restrict__ Bs,
                                              const float* __restrict__ Bd,
                                              const float* __restrict__ al,
                                              const float* __restrict__ ar,
                                              float* __restrict__ fs,
                                              float* __restrict__ el,
                                              float* __restrict__ er) {
    __shared__ float As[128 * LDA];
    int tid = threadIdx.x;
    int tc = tid & 15, tr = tid >> 4;
    int r0 = blockIdx.x * 64;
    int j0 = tc * 8;
    int rowA = tid & 63;
    int kc = tid >> 6;
    float as_[4][8], ad_[4][8];
    #pragma unroll
    for (int i = 0; i < 4; i++)
        #pragma unroll
        for (int c = 0; c < 8; c++) { as_[i][c] = 0.f; ad_[i][c] = 0.f; }

    int gr = r0 + rowA; if (gr > N_NODES - 1) gr = N_NODES - 1;
    const float* ap = A + (size_t)gr * HID + kc * 32;
    #pragma unroll
    for (int i = 0; i < 8; i++) {
        float4 v = ((const float4*)ap)[i];
        int k = kc * 32 + i * 4;
        As[(k + 0) * LDA + rowA] = v.x;
        As[(k + 1) * LDA + rowA] = v.y;
        As[(k + 2) * LDA + rowA] = v.z;
        As[(k + 3) * LDA + rowA] = v.w;
    }
    __syncthreads();
    const float* bps = Bs + j0;
    const float* bpd = Bd + j0;
    #pragma unroll 2
    for (int k = 0; k < 128; k++) {
        float4 a4 = *(const float4*)&As[k * LDA + tr * 4];
        float4 s0 = *(const float4*)&bps[(size_t)k * HID];
        float4 s1 = *(const float4*)&bps[(size_t)k * HID + 4];
        float4 d0 = *(const float4*)&bpd[(size_t)k * HID];
        float4 d1 = *(const float4*)&bpd[(size_t)k * HID + 4];
        float av[4] = {a4.x, a4.y, a4.z, a4.w};
        float sv[8] = {s0.x, s0.y, s0.z, s0.w, s1.x, s1.y, s1.z, s1.w};
        float dv[8] = {d0.x, d0.y, d0.z, d0.w, d1.x, d1.y, d1.z, d1.w};
        #pragma unroll
        for (int i = 0; i < 4; i++)
            #pragma unroll
            for (int c = 0; c < 8; c++) {
                as_[i][c] += av[i] * sv[c];
                ad_[i][c] += av[i] * dv[c];
            }
    }
    float alv[8], arv[8];
    #pragma unroll
    for (int c = 0; c < 8; c++) { alv[c] = al[j0 + c]; arv[c] = ar[j0 + c]; }
    int head = tc >> 1;
    #pragma unroll
    for (int i = 0; i < 4; i++) {
        int row = r0 + tr * 4 + i;
        bool ok = (row < N_NODES);
        if (ok) {
            float4 o0 = {as_[i][0], as_[i][1], as_[i][2], as_[i][3]};
            float4 o1 = {as_[i][4], as_[i][5], as_[i][6], as_[i][7]};
            *(float4*)&fs[(size_t)row * HID + j0] = o0;
            *(float4*)&fs[(size_t)row * HID + j0 + 4] = o1;
        }
        float pl = 0.f, pr = 0.f;
        #pragma unroll
        for (int c = 0; c < 8; c++) { pl += as_[i][c] * alv[c]; pr += ad_[i][c] * arv[c]; }
        pl += __shfl_xor(pl, 1);
        pr += __shfl_xor(pr, 1);
        if (ok && (tc & 1) == 0) {
            el[row * NH + head] = pl;
            er[row * NH + head] = pr;
        }
    }
}

// ---------------- K3: per-dst GAT aggregation; stores ELU(z) ----------------
__global__ __launch_bounds__(128) void k_gat(const int* __restrict__ ssrc,
                                             const int* __restrict__ offs,
                                             const float* __restrict__ el,
                                             const float* __restrict__ er,
                                             const float* __restrict__ fs,
                                             float* __restrict__ z, int m) {
    __shared__ float lds_part[128];
    __shared__ float inv_sum[NH];
    int d = blockIdx.x;
    int j = threadIdx.x;
    int s0 = offs[d], s1 = offs[d + 1];
    int t = j >> 3, hh2 = j & 7;
    float erd2 = er[d * NH + hh2];
    float part = 0.f;
    for (int i = s0 + t; i < s1; i += 16) {
        int s = ssrc[i];
        float x = el[s * NH + hh2] + erd2;
        x = (x >= 0.f) ? x : NEG * x;
        part += __expf(x);
    }
    lds_part[j] = part;
    __syncthreads();
    if (j < NH) {
        float acc = 0.f;
        #pragma unroll
        for (int t2 = 0; t2 < 16; t2++) acc += lds_part[t2 * 8 + j];
        inv_sum[j] = 1.f / fmaxf(acc, 1e-9f);
    }
    __syncthreads();
    int hh = j >> 4;
    float erd = er[d * NH + hh];
    float inv = inv_sum[hh];
    float acc = 0.f;
    for (int i = s0; i < s1; i++) {
        int s = ssrc[i];
        float x = el[s * NH + hh] + erd;
        x = (x >= 0.f) ? x : NEG * x;
        float alpha = __expf(x) * inv;
        acc += fs[(size_t)s * HID + j] * alpha;
    }
    z[(size_t)(d * NM + m) * HID + j] = (acc > 0.f) ? acc : (__expf(acc) - 1.f);
}

// -------- K4: w[r] = tanh(zel@W1 + b1) @ w2  (LDS-tiled, 64 rows/block) -------
__global__ __launch_bounds__(256) void k_semw(const float* __restrict__ A,
                                              const float* __restrict__ B,
                                              const float* __restrict__ b1,
                                              const float* __restrict__ ws2,
                                              float* __restrict__ w) {
    __shared__ float As[128 * LDA];
    int tid = threadIdx.x;
    int tc = tid & 15, tr = tid >> 4;
    int r0 = blockIdx.x * 64;
    int j0 = tc * 8;
    int rowA = tid & 63;
    int kc = tid >> 6;
    float acc[4][8];
    #pragma unroll
    for (int i = 0; i < 4; i++)
        #pragma unroll
        for (int c = 0; c < 8; c++) acc[i][c] = 0.f;

    int gr = r0 + rowA; if (gr > NROWS - 1) gr = NROWS - 1;
    const float* ap = A + (size_t)gr * HID + kc * 32;
    #pragma unroll
    for (int i = 0; i < 8; i++) {
        float4 v = ((const float4*)ap)[i];
        int k = kc * 32 + i * 4;
        As[(k + 0) * LDA + rowA] = v.x;
        As[(k + 1) * LDA + rowA] = v.y;
        As[(k + 2) * LDA + rowA] = v.z;
        As[(k + 3) * LDA + rowA] = v.w;
    }
    __syncthreads();
    const float* bp = B + j0;
    #pragma unroll 4
    for (int k = 0; k < 128; k++) {
        float4 a4 = *(const float4*)&As[k * LDA + tr * 4];
        float4 b0 = *(const float4*)&bp[(size_t)k * HID];
        float4 b1v = *(const float4*)&bp[(size_t)k * HID + 4];
        float av[4] = {a4.x, a4.y, a4.z, a4.w};
        float bv[8] = {b0.x, b0.y, b0.z, b0.w, b1v.x, b1v.y, b1v.z, b1v.w};
        #pragma unroll
        for (int i = 0; i < 4; i++)
            #pragma unroll
            for (int c = 0; c < 8; c++) acc[i][c] += av[i] * bv[c];
    }
    float bb[8], s2[8];
    #pragma unroll
    for (int c = 0; c < 8; c++) { bb[c] = b1[j0 + c]; s2[c] = ws2[j0 + c]; }
    #pragma unroll
    for (int i = 0; i < 4; i++) {
        float v = 0.f;
        #pragma unroll
        for (int c = 0; c < 8; c++) v += tanhf(acc[i][c] + bb[c]) * s2[c];
        #pragma unroll
        for (int o = 8; o > 0; o >>= 1) v += __shfl_down(v, o, 16);
        int row = r0 + tr * 4 + i;
        if (tc == 0 && row < NROWS) w[row] = v;
    }
}

// ---------------- K5: beta softmax + fused + out ----------------
__global__ __launch_bounds__(256) void k_comb(const float* __restrict__ zel,
                                              const float* __restrict__ w,
                                              const float* __restrict__ Wout,
                                              const float* __restrict__ bout,
                                              float* __restrict__ out) {
    __shared__ float fusedL[2][HID];
    int half = threadIdx.x >> 7;
    int j = threadIdx.x & 127;
    int n = blockIdx.x * 2 + half;
    float w0 = w[n * NM + 0];
    float w1 = w[n * NM + 1];
    float w2 = w[n * NM + 2];
    float mx = fmaxf(w0, fmaxf(w1, w2));
    float e0 = __expf(w0 - mx);
    float e1 = __expf(w1 - mx);
    float e2 = __expf(w2 - mx);
    float inv = 1.f / (e0 + e1 + e2);
    size_t base = (size_t)n * NM * HID;
    float f = (e0 * zel[base + j] + e1 * zel[base + HID + j] + e2 * zel[base + 2 * HID + j]) * inv;
    fusedL[half][j] = f;
    __syncthreads();
    int c = j >> 4, t16 = j & 15;
    float p = 0.f;
    #pragma unroll
    for (int i = 0; i < 8; i++) {
        int jj = t16 + i * 16;
        p += fusedL[half][jj] * Wout[jj * NOUT + c];
    }
    #pragma unroll
    for (int o = 8; o > 0; o >>= 1) p += __shfl_down(p, o, 16);
    if (t16 == 0) out[n * NOUT + c] = p + bout[c];
}

extern "C" void kernel_launch(void* const* d_in, const int* in_sizes, int n_in,
                              void* d_out, int out_size, void* d_ws, size_t ws_size,
                              hipStream_t stream) {
    (void)in_sizes; (void)n_in; (void)out_size; (void)ws_size;
    const float* feat  = (const float*)d_in[0];
    const float* Wfc   = (const float*)d_in[1];
    const float* bfc   = (const float*)d_in[2];
    const float* Wsrc  = (const float*)d_in[3];
    const float* Wdst  = (const float*)d_in[4];
    const float* al    = (const float*)d_in[5];
    const float* ar    = (const float*)d_in[6];
    const float* Wsem1 = (const float*)d_in[7];
    const float* bsem1 = (const float*)d_in[8];
    const float* wsem2 = (const float*)d_in[9];
    const float* Wout  = (const float*)d_in[10];
    const float* bout  = (const float*)d_in[11];
    const int* srcI    = (const int*)d_in[12];
    const int* dstI    = (const int*)d_in[13];
    float* out = (float*)d_out;

    // fp32 section
    float* h    = (float*)d_ws;
    float* z    = h  + (size_t)N_NODES * HID;
    float* fs   = z  + (size_t)N_NODES * NM * HID;
    float* el   = fs + (size_t)N_NODES * HID;
    float* er   = el + (size_t)N_NODES * NH;
    float* wsc  = er + (size_t)N_NODES * NH;
    // int section
    int* deg    = (int*)(wsc + (size_t)NROWS);
    int* offs   = deg    + (size_t)NM * N_NODES;
    int* ssrc   = offs   + (size_t)NM * (N_NODES + 1);
    int* pfx    = ssrc   + (size_t)NM * NE;
    int* dstCur = pfx    + (size_t)NM * N_NODES;
    int* blksum = dstCur + (size_t)NM * N_NODES;
    int* blkbase= blksum + (size_t)NM * NBLK;
    int* binCur = blkbase+ (size_t)NM * NBLK;
    int2* pairs = (int2*)((((uintptr_t)(binCur + (size_t)NM * NBUCK)) + 15) & ~(uintptr_t)15);

    // ---- CSR build ----
    hipMemsetAsync(deg, 0, (size_t)NM * N_NODES * sizeof(int), stream);
    {
        dim3 ge((NE + 255) / 256, NM);
        dim3 gs(NBLK, NM);
        k_hist<<<ge, 256, 0, stream>>>(dstI, deg);
        k_scan1<<<gs, 256, 0, stream>>>(deg, pfx, blksum);
        k_scan2<<<NM, 256, 0, stream>>>(blksum, blkbase);
        k_scan3<<<gs, 256, 0, stream>>>(pfx, blkbase, offs, dstCur, binCur);
        for (int m = 0; m < NM; m++) {
            k_binA2<<<(NE + EPB - 1) / EPB, 256, 0, stream>>>(srcI + (size_t)m * NE,
                                                              dstI + (size_t)m * NE,
                                                              binCur + (size_t)m * NBUCK, pairs);
            k_binB<<<(NE + 255) / 256, 256, 0, stream>>>(pairs,
                                                         dstCur + (size_t)m * N_NODES,
                                                         ssrc + (size_t)m * NE);
        }
    }

    k_fc<<<(N_NODES + 63) / 64, 256, 0, stream>>>(feat, Wfc, bfc, h);

    for (int m = 0; m < NM; m++) {
        k_proj<<<(N_NODES + 63) / 64, 256, 0, stream>>>(h, Wsrc + (size_t)m * HID * HID,
                                                        Wdst + (size_t)m * HID * HID,
                                                        al + m * NH * DH, ar + m * NH * DH,
                                                        fs, el, er);
        k_gat<<<N_NODES, 128, 0, stream>>>(ssrc + (size_t)m * NE,
                                           offs + (size_t)m * (N_NODES + 1),
                                           el, er, fs, z, m);
    }

    k_semw<<<(NROWS + 63) / 64, 256, 0, stream>>>(z, Wsem1, bsem1, wsem2, wsc);
    k_comb<<<N_NODES / 2, 256, 0, stream>>>(z, wsc, Wout, bout, out);
}

// Round 9
// 1014.602 us; speedup vs baseline: 1.6507x; 1.1492x over previous
//
#include <hip/hip_runtime.h>
#include <hip/hip_bf16.h>
#include <stdint.h>

#define N_NODES 50000
#define F_IN 256
#define HID 128
#define NH 8
#define DH 16
#define NE 800000
#define NM 3
#define NOUT 8
#define NEG 0.2f
#define NROWS (N_NODES * NM)   // 150000 semantic rows
#define LDA 68                 // padded LDS stride for GEMM tiles
#define NBLK 196               // ceil(50000/256) scan blocks
#define BSH 8                  // bucket shift: 256 dst per bucket
#define NBUCK 196              // ceil(50000/256)
#define EPB 8192               // edges per binning block

__device__ __forceinline__ float bf2f(unsigned short u) {
    union { unsigned int ui; float f; } cv;
    cv.ui = ((unsigned int)u) << 16;
    return cv.f;
}
__device__ __forceinline__ unsigned short f2bf(float x) {
    __hip_bfloat16 b = __float2bfloat16(x);
    return reinterpret_cast<const unsigned short&>(b);
}

// ---------------- CSR build ----------------
__global__ __launch_bounds__(256) void k_hist(const int* __restrict__ dst,
                                              int* __restrict__ deg) {
    int e = blockIdx.x * 256 + threadIdx.x;
    int m = blockIdx.y;
    if (e >= NE) return;
    atomicAdd(&deg[m * N_NODES + dst[(size_t)m * NE + e]], 1);
}

__global__ __launch_bounds__(256) void k_scan1(const int* __restrict__ deg,
                                               int* __restrict__ pfx,
                                               int* __restrict__ blksum) {
    __shared__ int sc[256];
    int m = blockIdx.y, blk = blockIdx.x, t = threadIdx.x;
    int i = blk * 256 + t;
    int v = (i < N_NODES) ? deg[m * N_NODES + i] : 0;
    sc[t] = v;
    __syncthreads();
    #pragma unroll
    for (int o = 1; o < 256; o <<= 1) {
        int add = (t >= o) ? sc[t - o] : 0;
        __syncthreads();
        sc[t] += add;
        __syncthreads();
    }
    if (i < N_NODES) pfx[m * N_NODES + i] = sc[t] - v;
    if (t == 255) blksum[m * NBLK + blk] = sc[255];
}

__global__ __launch_bounds__(256) void k_scan2(const int* __restrict__ blksum,
                                               int* __restrict__ blkbase) {
    __shared__ int sc[256];
    int m = blockIdx.x, t = threadIdx.x;
    int v = (t < NBLK) ? blksum[m * NBLK + t] : 0;
    sc[t] = v;
    __syncthreads();
    #pragma unroll
    for (int o = 1; o < 256; o <<= 1) {
        int add = (t >= o) ? sc[t - o] : 0;
        __syncthreads();
        sc[t] += add;
        __syncthreads();
    }
    if (t < NBLK) blkbase[m * NBLK + t] = sc[t] - v;
}

__global__ __launch_bounds__(256) void k_scan3(const int* __restrict__ pfx,
                                               const int* __restrict__ blkbase,
                                               int* __restrict__ offs,
                                               int* __restrict__ dstCur,
                                               int* __restrict__ binCur) {
    int m = blockIdx.y, blk = blockIdx.x, t = threadIdx.x;
    int i = blk * 256 + t;
    if (i < N_NODES) {
        int o = blkbase[m * NBLK + blk] + pfx[m * N_NODES + i];
        offs[m * (N_NODES + 1) + i] = o;
        dstCur[m * N_NODES + i] = o;
        if ((i & 255) == 0) binCur[m * NBUCK + (i >> BSH)] = o;
    }
    if (i == 0) offs[m * (N_NODES + 1) + N_NODES] = NE;
}

// phase A: block-local count -> one reservation atomic per (block,bucket)
__global__ __launch_bounds__(256) void k_binA2(const int* __restrict__ src,
                                               const int* __restrict__ dst,
                                               int* __restrict__ binCur,
                                               int2* __restrict__ pairs) {
    __shared__ int cnt[NBUCK];
    __shared__ int base[NBUCK];
    int t = threadIdx.x;
    int e0 = blockIdx.x * EPB;
    int e1 = e0 + EPB; if (e1 > NE) e1 = NE;
    for (int i = t; i < NBUCK; i += 256) cnt[i] = 0;
    __syncthreads();
    for (int i = e0 + t; i < e1; i += 256)
        atomicAdd(&cnt[dst[i] >> BSH], 1);
    __syncthreads();
    for (int i = t; i < NBUCK; i += 256) {
        int c = cnt[i];
        base[i] = c ? atomicAdd(&binCur[i], c) : 0;
        cnt[i] = 0;
    }
    __syncthreads();
    for (int i = e0 + t; i < e1; i += 256) {
        int d = dst[i], s = src[i];
        int b = d >> BSH;
        int off = atomicAdd(&cnt[b], 1);
        pairs[base[b] + off] = make_int2(s, d);
    }
}

// phase B: within-bucket scatter (L2-resident windows)
__global__ __launch_bounds__(256) void k_binB(const int2* __restrict__ pairs,
                                              int* __restrict__ dstCur,
                                              int* __restrict__ ssrc) {
    int i = blockIdx.x * 256 + threadIdx.x;
    if (i >= NE) return;
    int2 p = pairs[i];
    int pos = atomicAdd(&dstCur[p.y], 1);
    ssrc[pos] = p.x;
}

// ---------------- K1: h = feat @ W_fc + b (LDS-tiled, 64 rows/block) ----------
__global__ __launch_bounds__(256) void k_fc(const float* __restrict__ A,
                                            const float* __restrict__ B,
                                            const float* __restrict__ bias,
                                            float* __restrict__ C) {
    __shared__ float As[128 * LDA];
    int tid = threadIdx.x;
    int tc = tid & 15, tr = tid >> 4;
    int r0 = blockIdx.x * 64;
    int j0 = tc * 8;
    int rowA = tid & 63;
    int kc = tid >> 6;
    float acc[4][8];
    #pragma unroll
    for (int i = 0; i < 4; i++)
        #pragma unroll
        for (int c = 0; c < 8; c++) acc[i][c] = 0.f;

    int gr = r0 + rowA; if (gr > N_NODES - 1) gr = N_NODES - 1;
    for (int ph = 0; ph < 2; ph++) {
        __syncthreads();
        const float* ap = A + (size_t)gr * F_IN + ph * 128 + kc * 32;
        #pragma unroll
        for (int i = 0; i < 8; i++) {
            float4 v = ((const float4*)ap)[i];
            int k = kc * 32 + i * 4;
            As[(k + 0) * LDA + rowA] = v.x;
            As[(k + 1) * LDA + rowA] = v.y;
            As[(k + 2) * LDA + rowA] = v.z;
            As[(k + 3) * LDA + rowA] = v.w;
        }
        __syncthreads();
        const float* bp = B + (size_t)(ph * 128) * HID + j0;
        #pragma unroll 4
        for (int k = 0; k < 128; k++) {
            float4 a4 = *(const float4*)&As[k * LDA + tr * 4];
            float4 b0 = *(const float4*)&bp[(size_t)k * HID];
            float4 b1 = *(const float4*)&bp[(size_t)k * HID + 4];
            float av[4] = {a4.x, a4.y, a4.z, a4.w};
            float bv[8] = {b0.x, b0.y, b0.z, b0.w, b1.x, b1.y, b1.z, b1.w};
            #pragma unroll
            for (int i = 0; i < 4; i++)
                #pragma unroll
                for (int c = 0; c < 8; c++) acc[i][c] += av[i] * bv[c];
        }
    }
    float bb[8];
    #pragma unroll
    for (int c = 0; c < 8; c++) bb[c] = bias[j0 + c];
    #pragma unroll
    for (int i = 0; i < 4; i++) {
        int row = r0 + tr * 4 + i;
        if (row < N_NODES) {
            float4 o0 = {acc[i][0] + bb[0], acc[i][1] + bb[1], acc[i][2] + bb[2], acc[i][3] + bb[3]};
            float4 o1 = {acc[i][4] + bb[4], acc[i][5] + bb[5], acc[i][6] + bb[6], acc[i][7] + bb[7]};
            *(float4*)&C[(size_t)row * HID + j0] = o0;
            *(float4*)&C[(size_t)row * HID + j0 + 4] = o1;
        }
    }
}

// ------- K2: fs(bf16) = h@Wsrc, fd = h@Wdst (el/er only) -------
__global__ __launch_bounds__(256) void k_proj(const float* __restrict__ A,
                                              const float* __restrict__ Bs,
                                              const float* __restrict__ Bd,
                                              const float* __restrict__ al,
                                              const float* __restrict__ ar,
                                              unsigned short* __restrict__ fs16,
                                              float* __restrict__ el,
                                              float* __restrict__ er) {
    __shared__ float As[128 * LDA];
    int tid = threadIdx.x;
    int tc = tid & 15, tr = tid >> 4;
    int r0 = blockIdx.x * 64;
    int j0 = tc * 8;
    int rowA = tid & 63;
    int kc = tid >> 6;
    float as_[4][8], ad_[4][8];
    #pragma unroll
    for (int i = 0; i < 4; i++)
        #pragma unroll
        for (int c = 0; c < 8; c++) { as_[i][c] = 0.f; ad_[i][c] = 0.f; }

    int gr = r0 + rowA; if (gr > N_NODES - 1) gr = N_NODES - 1;
    const float* ap = A + (size_t)gr * HID + kc * 32;
    #pragma unroll
    for (int i = 0; i < 8; i++) {
        float4 v = ((const float4*)ap)[i];
        int k = kc * 32 + i * 4;
        As[(k + 0) * LDA + rowA] = v.x;
        As[(k + 1) * LDA + rowA] = v.y;
        As[(k + 2) * LDA + rowA] = v.z;
        As[(k + 3) * LDA + rowA] = v.w;
    }
    __syncthreads();
    const float* bps = Bs + j0;
    const float* bpd = Bd + j0;
    #pragma unroll 2
    for (int k = 0; k < 128; k++) {
        float4 a4 = *(const float4*)&As[k * LDA + tr * 4];
        float4 s0 = *(const float4*)&bps[(size_t)k * HID];
        float4 s1 = *(const float4*)&bps[(size_t)k * HID + 4];
        float4 d0 = *(const float4*)&bpd[(size_t)k * HID];
        float4 d1 = *(const float4*)&bpd[(size_t)k * HID + 4];
        float av[4] = {a4.x, a4.y, a4.z, a4.w};
        float sv[8] = {s0.x, s0.y, s0.z, s0.w, s1.x, s1.y, s1.z, s1.w};
        float dv[8] = {d0.x, d0.y, d0.z, d0.w, d1.x, d1.y, d1.z, d1.w};
        #pragma unroll
        for (int i = 0; i < 4; i++)
            #pragma unroll
            for (int c = 0; c < 8; c++) {
                as_[i][c] += av[i] * sv[c];
                ad_[i][c] += av[i] * dv[c];
            }
    }
    float alv[8], arv[8];
    #pragma unroll
    for (int c = 0; c < 8; c++) { alv[c] = al[j0 + c]; arv[c] = ar[j0 + c]; }
    int head = tc >> 1;
    #pragma unroll
    for (int i = 0; i < 4; i++) {
        int row = r0 + tr * 4 + i;
        bool ok = (row < N_NODES);
        if (ok) {
            union { unsigned short us[8]; uint4 v; } pk;
            #pragma unroll
            for (int c = 0; c < 8; c++) pk.us[c] = f2bf(as_[i][c]);
            *(uint4*)&fs16[(size_t)row * HID + j0] = pk.v;
        }
        float pl = 0.f, pr = 0.f;
        #pragma unroll
        for (int c = 0; c < 8; c++) { pl += as_[i][c] * alv[c]; pr += ad_[i][c] * arv[c]; }
        pl += __shfl_xor(pl, 1);
        pr += __shfl_xor(pr, 1);
        if (ok && (tc & 1) == 0) {
            el[row * NH + head] = pl;
            er[row * NH + head] = pr;
        }
    }
}

// ---- K3: per-dst GAT aggregation, single pass (z = Σe·fs / Σe), no barriers ----
__global__ __launch_bounds__(128) void k_gat(const int* __restrict__ ssrc,
                                             const int* __restrict__ offs,
                                             const float* __restrict__ el,
                                             const float* __restrict__ er,
                                             const unsigned short* __restrict__ fs16,
                                             float* __restrict__ z, int m) {
    int d = blockIdx.x;
    int j = threadIdx.x;
    int hh = j >> 4;
    int s0 = offs[d], s1 = offs[d + 1];
    float erd = er[d * NH + hh];
    float num = 0.f, den = 0.f;
    int i = s0;
    for (; i + 2 <= s1; i += 2) {
        int sa = ssrc[i], sb = ssrc[i + 1];
        float xa = el[sa * NH + hh] + erd;
        float xb = el[sb * NH + hh] + erd;
        unsigned short ua = fs16[(size_t)sa * HID + j];
        unsigned short ub = fs16[(size_t)sb * HID + j];
        xa = (xa >= 0.f) ? xa : NEG * xa;
        xb = (xb >= 0.f) ? xb : NEG * xb;
        float ea = __expf(xa), eb = __expf(xb);
        den += ea + eb;
        num += ea * bf2f(ua) + eb * bf2f(ub);
    }
    if (i < s1) {
        int s = ssrc[i];
        float x = el[s * NH + hh] + erd;
        x = (x >= 0.f) ? x : NEG * x;
        float e = __expf(x);
        den += e;
        num += e * bf2f(fs16[(size_t)s * HID + j]);
    }
    float val = num / fmaxf(den, 1e-9f);
    z[(size_t)(d * NM + m) * HID + j] = (val > 0.f) ? val : (__expf(val) - 1.f);
}

// -------- K4: w[r] = tanh(zel@W1 + b1) @ w2  (LDS-tiled, 64 rows/block) -------
__global__ __launch_bounds__(256) void k_semw(const float* __restrict__ A,
                                              const float* __restrict__ B,
                                              const float* __restrict__ b1,
                                              const float* __restrict__ ws2,
                                              float* __restrict__ w) {
    __shared__ float As[128 * LDA];
    int tid = threadIdx.x;
    int tc = tid & 15, tr = tid >> 4;
    int r0 = blockIdx.x * 64;
    int j0 = tc * 8;
    int rowA = tid & 63;
    int kc = tid >> 6;
    float acc[4][8];
    #pragma unroll
    for (int i = 0; i < 4; i++)
        #pragma unroll
        for (int c = 0; c < 8; c++) acc[i][c] = 0.f;

    int gr = r0 + rowA; if (gr > NROWS - 1) gr = NROWS - 1;
    const float* ap = A + (size_t)gr * HID + kc * 32;
    #pragma unroll
    for (int i = 0; i < 8; i++) {
        float4 v = ((const float4*)ap)[i];
        int k = kc * 32 + i * 4;
        As[(k + 0) * LDA + rowA] = v.x;
        As[(k + 1) * LDA + rowA] = v.y;
        As[(k + 2) * LDA + rowA] = v.z;
        As[(k + 3) * LDA + rowA] = v.w;
    }
    __syncthreads();
    const float* bp = B + j0;
    #pragma unroll 4
    for (int k = 0; k < 128; k++) {
        float4 a4 = *(const float4*)&As[k * LDA + tr * 4];
        float4 b0 = *(const float4*)&bp[(size_t)k * HID];
        float4 b1v = *(const float4*)&bp[(size_t)k * HID + 4];
        float av[4] = {a4.x, a4.y, a4.z, a4.w};
        float bv[8] = {b0.x, b0.y, b0.z, b0.w, b1v.x, b1v.y, b1v.z, b1v.w};
        #pragma unroll
        for (int i = 0; i < 4; i++)
            #pragma unroll
            for (int c = 0; c < 8; c++) acc[i][c] += av[i] * bv[c];
    }
    float bb[8], s2[8];
    #pragma unroll
    for (int c = 0; c < 8; c++) { bb[c] = b1[j0 + c]; s2[c] = ws2[j0 + c]; }
    #pragma unroll
    for (int i = 0; i < 4; i++) {
        float v = 0.f;
        #pragma unroll
        for (int c = 0; c < 8; c++) v += tanhf(acc[i][c] + bb[c]) * s2[c];
        #pragma unroll
        for (int o = 8; o > 0; o >>= 1) v += __shfl_down(v, o, 16);
        int row = r0 + tr * 4 + i;
        if (tc == 0 && row < NROWS) w[row] = v;
    }
}

// ---------------- K5: beta softmax + fused + out ----------------
__global__ __launch_bounds__(256) void k_comb(const float* __restrict__ zel,
                                              const float* __restrict__ w,
                                              const float* __restrict__ Wout,
                                              const float* __restrict__ bout,
                                              float* __restrict__ out) {
    __shared__ float fusedL[2][HID];
    int half = threadIdx.x >> 7;
    int j = threadIdx.x & 127;
    int n = blockIdx.x * 2 + half;
    float w0 = w[n * NM + 0];
    float w1 = w[n * NM + 1];
    float w2 = w[n * NM + 2];
    float mx = fmaxf(w0, fmaxf(w1, w2));
    float e0 = __expf(w0 - mx);
    float e1 = __expf(w1 - mx);
    float e2 = __expf(w2 - mx);
    float inv = 1.f / (e0 + e1 + e2);
    size_t base = (size_t)n * NM * HID;
    float f = (e0 * zel[base + j] + e1 * zel[base + HID + j] + e2 * zel[base + 2 * HID + j]) * inv;
    fusedL[half][j] = f;
    __syncthreads();
    int c = j >> 4, t16 = j & 15;
    float p = 0.f;
    #pragma unroll
    for (int i = 0; i < 8; i++) {
        int jj = t16 + i * 16;
        p += fusedL[half][jj] * Wout[jj * NOUT + c];
    }
    #pragma unroll
    for (int o = 8; o > 0; o >>= 1) p += __shfl_down(p, o, 16);
    if (t16 == 0) out[n * NOUT + c] = p + bout[c];
}

extern "C" void kernel_launch(void* const* d_in, const int* in_sizes, int n_in,
                              void* d_out, int out_size, void* d_ws, size_t ws_size,
                              hipStream_t stream) {
    (void)in_sizes; (void)n_in; (void)out_size; (void)ws_size;
    const float* feat  = (const float*)d_in[0];
    const float* Wfc   = (const float*)d_in[1];
    const float* bfc   = (const float*)d_in[2];
    const float* Wsrc  = (const float*)d_in[3];
    const float* Wdst  = (const float*)d_in[4];
    const float* al    = (const float*)d_in[5];
    const float* ar    = (const float*)d_in[6];
    const float* Wsem1 = (const float*)d_in[7];
    const float* bsem1 = (const float*)d_in[8];
    const float* wsem2 = (const float*)d_in[9];
    const float* Wout  = (const float*)d_in[10];
    const float* bout  = (const float*)d_in[11];
    const int* srcI    = (const int*)d_in[12];
    const int* dstI    = (const int*)d_in[13];
    float* out = (float*)d_out;

    // fp32 section
    float* h    = (float*)d_ws;
    float* z    = h  + (size_t)N_NODES * HID;
    float* el   = z  + (size_t)N_NODES * NM * HID;
    float* er   = el + (size_t)N_NODES * NH;
    float* wsc  = er + (size_t)N_NODES * NH;
    // bf16 fs (16B-aligned)
    unsigned short* fs16 = (unsigned short*)((((uintptr_t)(wsc + (size_t)NROWS)) + 15) & ~(uintptr_t)15);
    // int section
    int* deg    = (int*)(fs16 + (size_t)N_NODES * HID);
    int* offs   = deg    + (size_t)NM * N_NODES;
    int* ssrc   = offs   + (size_t)NM * (N_NODES + 1);
    int* pfx    = ssrc   + (size_t)NM * NE;
    int* dstCur = pfx    + (size_t)NM * N_NODES;
    int* blksum = dstCur + (size_t)NM * N_NODES;
    int* blkbase= blksum + (size_t)NM * NBLK;
    int* binCur = blkbase+ (size_t)NM * NBLK;
    int2* pairs = (int2*)((((uintptr_t)(binCur + (size_t)NM * NBUCK)) + 15) & ~(uintptr_t)15);

    // ---- CSR build ----
    hipMemsetAsync(deg, 0, (size_t)NM * N_NODES * sizeof(int), stream);
    {
        dim3 ge((NE + 255) / 256, NM);
        dim3 gs(NBLK, NM);
        k_hist<<<ge, 256, 0, stream>>>(dstI, deg);
        k_scan1<<<gs, 256, 0, stream>>>(deg, pfx, blksum);
        k_scan2<<<NM, 256, 0, stream>>>(blksum, blkbase);
        k_scan3<<<gs, 256, 0, stream>>>(pfx, blkbase, offs, dstCur, binCur);
        for (int m = 0; m < NM; m++) {
            k_binA2<<<(NE + EPB - 1) / EPB, 256, 0, stream>>>(srcI + (size_t)m * NE,
                                                              dstI + (size_t)m * NE,
                                                              binCur + (size_t)m * NBUCK, pairs);
            k_binB<<<(NE + 255) / 256, 256, 0, stream>>>(pairs,
                                                         dstCur + (size_t)m * N_NODES,
                                                         ssrc + (size_t)m * NE);
        }
    }

    k_fc<<<(N_NODES + 63) / 64, 256, 0, stream>>>(feat, Wfc, bfc, h);

    for (int m = 0; m < NM; m++) {
        k_proj<<<(N_NODES + 63) / 64, 256, 0, stream>>>(h, Wsrc + (size_t)m * HID * HID,
                                                        Wdst + (size_t)m * HID * HID,
                                                        al + m * NH * DH, ar + m * NH * DH,
                                                        fs16, el, er);
        k_gat<<<N_NODES, 128, 0, stream>>>(ssrc + (size_t)m * NE,
                                           offs + (size_t)m * (N_NODES + 1),
                                           el, er, fs16, z, m);
    }

    k_semw<<<(NROWS + 63) / 64, 256, 0, stream>>>(z, Wsem1, bsem1, wsem2, wsc);
    k_comb<<<N_NODES / 2, 256, 0, stream>>>(z, wsc, Wout, bout, out);
}

// Round 10
// 924.032 us; speedup vs baseline: 1.8125x; 1.0980x over previous
//
#include <hip/hip_runtime.h>
#include <hip/hip_bf16.h>
#include <stdint.h>

#define N_NODES 50000
#define F_IN 256
#define HID 128
#define NH 8
#define DH 16
#define NE 800000
#define NM 3
#define NOUT 8
#define NEG 0.2f
#define NROWS (N_NODES * NM)   // 150000 semantic rows
#define LDA 68                 // padded fp32 LDS stride (k_fc)
#define LDP 68                 // padded uint (k-pair) LDS stride (bf16 tiles)
#define NBLK 196               // ceil(50000/256) scan blocks
#define BSH 8                  // bucket shift: 256 dst per bucket
#define NBUCK 196              // ceil(50000/256)
#define EPB 8192               // edges per binning block

__device__ __forceinline__ float bf2f(unsigned short u) {
    union { unsigned int ui; float f; } cv;
    cv.ui = ((unsigned int)u) << 16;
    return cv.f;
}
__device__ __forceinline__ unsigned short f2bf(float x) {
    __hip_bfloat16 b = __float2bfloat16(x);
    return reinterpret_cast<const unsigned short&>(b);
}
__device__ __forceinline__ float bflo(unsigned int u) {
    union { unsigned int x; float f; } c; c.x = u << 16; return c.f;
}
__device__ __forceinline__ float bfhi(unsigned int u) {
    union { unsigned int x; float f; } c; c.x = u & 0xffff0000u; return c.f;
}

// ---------------- CSR build ----------------
__global__ __launch_bounds__(256) void k_hist(const int* __restrict__ dst,
                                              int* __restrict__ deg) {
    int e = blockIdx.x * 256 + threadIdx.x;
    int m = blockIdx.y;
    if (e >= NE) return;
    atomicAdd(&deg[m * N_NODES + dst[(size_t)m * NE + e]], 1);
}

__global__ __launch_bounds__(256) void k_scan1(const int* __restrict__ deg,
                                               int* __restrict__ pfx,
                                               int* __restrict__ blksum) {
    __shared__ int sc[256];
    int m = blockIdx.y, blk = blockIdx.x, t = threadIdx.x;
    int i = blk * 256 + t;
    int v = (i < N_NODES) ? deg[m * N_NODES + i] : 0;
    sc[t] = v;
    __syncthreads();
    #pragma unroll
    for (int o = 1; o < 256; o <<= 1) {
        int add = (t >= o) ? sc[t - o] : 0;
        __syncthreads();
        sc[t] += add;
        __syncthreads();
    }
    if (i < N_NODES) pfx[m * N_NODES + i] = sc[t] - v;
    if (t == 255) blksum[m * NBLK + blk] = sc[255];
}

__global__ __launch_bounds__(256) void k_scan2(const int* __restrict__ blksum,
                                               int* __restrict__ blkbase) {
    __shared__ int sc[256];
    int m = blockIdx.x, t = threadIdx.x;
    int v = (t < NBLK) ? blksum[m * NBLK + t] : 0;
    sc[t] = v;
    __syncthreads();
    #pragma unroll
    for (int o = 1; o < 256; o <<= 1) {
        int add = (t >= o) ? sc[t - o] : 0;
        __syncthreads();
        sc[t] += add;
        __syncthreads();
    }
    if (t < NBLK) blkbase[m * NBLK + t] = sc[t] - v;
}

__global__ __launch_bounds__(256) void k_scan3(const int* __restrict__ pfx,
                                               const int* __restrict__ blkbase,
                                               int* __restrict__ offs,
                                               int* __restrict__ dstCur,
                                               int* __restrict__ binCur) {
    int m = blockIdx.y, blk = blockIdx.x, t = threadIdx.x;
    int i = blk * 256 + t;
    if (i < N_NODES) {
        int o = blkbase[m * NBLK + blk] + pfx[m * N_NODES + i];
        offs[m * (N_NODES + 1) + i] = o;
        dstCur[m * N_NODES + i] = o;
        if ((i & 255) == 0) binCur[m * NBUCK + (i >> BSH)] = o;
    }
    if (i == 0) offs[m * (N_NODES + 1) + N_NODES] = NE;
}

__global__ __launch_bounds__(256) void k_binA2(const int* __restrict__ src,
                                               const int* __restrict__ dst,
                                               int* __restrict__ binCur,
                                               int2* __restrict__ pairs) {
    __shared__ int cnt[NBUCK];
    __shared__ int base[NBUCK];
    int t = threadIdx.x;
    int e0 = blockIdx.x * EPB;
    int e1 = e0 + EPB; if (e1 > NE) e1 = NE;
    for (int i = t; i < NBUCK; i += 256) cnt[i] = 0;
    __syncthreads();
    for (int i = e0 + t; i < e1; i += 256)
        atomicAdd(&cnt[dst[i] >> BSH], 1);
    __syncthreads();
    for (int i = t; i < NBUCK; i += 256) {
        int c = cnt[i];
        base[i] = c ? atomicAdd(&binCur[i], c) : 0;
        cnt[i] = 0;
    }
    __syncthreads();
    for (int i = e0 + t; i < e1; i += 256) {
        int d = dst[i], s = src[i];
        int b = d >> BSH;
        int off = atomicAdd(&cnt[b], 1);
        pairs[base[b] + off] = make_int2(s, d);
    }
}

__global__ __launch_bounds__(256) void k_binB(const int2* __restrict__ pairs,
                                              int* __restrict__ dstCur,
                                              int* __restrict__ ssrc) {
    int i = blockIdx.x * 256 + threadIdx.x;
    if (i >= NE) return;
    int2 p = pairs[i];
    int pos = atomicAdd(&dstCur[p.y], 1);
    ssrc[pos] = p.x;
}

// ---------------- K1: h = feat @ W_fc + b (fp32 LDS, 64 rows/block) ----------
__global__ __launch_bounds__(256) void k_fc(const float* __restrict__ A,
                                            const float* __restrict__ B,
                                            const float* __restrict__ bias,
                                            float* __restrict__ C) {
    __shared__ float As[128 * LDA];
    int tid = threadIdx.x;
    int tc = tid & 15, tr = tid >> 4;
    int r0 = blockIdx.x * 64;
    int j0 = tc * 8;
    int rowA = tid & 63;
    int kc = tid >> 6;
    float acc[4][8];
    #pragma unroll
    for (int i = 0; i < 4; i++)
        #pragma unroll
        for (int c = 0; c < 8; c++) acc[i][c] = 0.f;

    int gr = r0 + rowA; if (gr > N_NODES - 1) gr = N_NODES - 1;
    for (int ph = 0; ph < 2; ph++) {
        __syncthreads();
        const float* ap = A + (size_t)gr * F_IN + ph * 128 + kc * 32;
        #pragma unroll
        for (int i = 0; i < 8; i++) {
            float4 v = ((const float4*)ap)[i];
            int k = kc * 32 + i * 4;
            As[(k + 0) * LDA + rowA] = v.x;
            As[(k + 1) * LDA + rowA] = v.y;
            As[(k + 2) * LDA + rowA] = v.z;
            As[(k + 3) * LDA + rowA] = v.w;
        }
        __syncthreads();
        const float* bp = B + (size_t)(ph * 128) * HID + j0;
        #pragma unroll 4
        for (int k = 0; k < 128; k++) {
            float4 a4 = *(const float4*)&As[k * LDA + tr * 4];
            float4 b0 = *(const float4*)&bp[(size_t)k * HID];
            float4 b1 = *(const float4*)&bp[(size_t)k * HID + 4];
            float av[4] = {a4.x, a4.y, a4.z, a4.w};
            float bv[8] = {b0.x, b0.y, b0.z, b0.w, b1.x, b1.y, b1.z, b1.w};
            #pragma unroll
            for (int i = 0; i < 4; i++)
                #pragma unroll
                for (int c = 0; c < 8; c++) acc[i][c] += av[i] * bv[c];
        }
    }
    float bb[8];
    #pragma unroll
    for (int c = 0; c < 8; c++) bb[c] = bias[j0 + c];
    #pragma unroll
    for (int i = 0; i < 4; i++) {
        int row = r0 + tr * 4 + i;
        if (row < N_NODES) {
            float4 o0 = {acc[i][0] + bb[0], acc[i][1] + bb[1], acc[i][2] + bb[2], acc[i][3] + bb[3]};
            float4 o1 = {acc[i][4] + bb[4], acc[i][5] + bb[5], acc[i][6] + bb[6], acc[i][7] + bb[7]};
            *(float4*)&C[(size_t)row * HID + j0] = o0;
            *(float4*)&C[(size_t)row * HID + j0 + 4] = o1;
        }
    }
}

// ---- K_attw: util[m][k][h] = sum_d Wsrc[m][k][h*16+d]*al[m][h*16+d]; same wtil/Wdst/ar ----
__global__ __launch_bounds__(128) void k_attw(const float* __restrict__ Wsrc,
                                              const float* __restrict__ Wdst,
                                              const float* __restrict__ al,
                                              const float* __restrict__ ar,
                                              float* __restrict__ util,
                                              float* __restrict__ wtil) {
    int m = blockIdx.x;
    int k = threadIdx.x;
    const float* ws = Wsrc + ((size_t)m * HID + k) * HID;
    const float* wd = Wdst + ((size_t)m * HID + k) * HID;
    const float* alm = al + m * HID;
    const float* arm = ar + m * HID;
    #pragma unroll
    for (int hh = 0; hh < NH; hh++) {
        float su = 0.f, sw = 0.f;
        #pragma unroll
        for (int d = 0; d < DH; d++) {
            su += ws[hh * DH + d] * alm[hh * DH + d];
            sw += wd[hh * DH + d] * arm[hh * DH + d];
        }
        util[((size_t)m * HID + k) * NH + hh] = su;
        wtil[((size_t)m * HID + k) * NH + hh] = sw;
    }
}

// ------- K2: fs16 = bf16(h@Wsrc); el = h@util, er = h@wtil (bf16 LDS A-tile) -------
__global__ __launch_bounds__(256) void k_proj(const float* __restrict__ A,
                                              const float* __restrict__ Bs0,
                                              const float* __restrict__ util0,
                                              const float* __restrict__ wtil0,
                                              unsigned short* __restrict__ fs0,
                                              float* __restrict__ el0,
                                              float* __restrict__ er0) {
    __shared__ unsigned int As2[64 * LDP];  // [k/2][row], (k,k+1) packed bf16
    int m = blockIdx.y;
    const float* Bs = Bs0 + (size_t)m * HID * HID;
    unsigned short* fs16 = fs0 + (size_t)m * N_NODES * HID;
    float* el = el0 + (size_t)m * N_NODES * NH;
    float* er = er0 + (size_t)m * N_NODES * NH;
    int tid = threadIdx.x;
    int tc = tid & 15, tr = tid >> 4;
    int r0 = blockIdx.x * 64;
    int j0 = tc * 8;
    int rowA = tid & 63;
    int kc = tid >> 6;
    float acc[4][8];
    float ae[4];
    #pragma unroll
    for (int i = 0; i < 4; i++) {
        ae[i] = 0.f;
        #pragma unroll
        for (int c = 0; c < 8; c++) acc[i][c] = 0.f;
    }
    int gr = r0 + rowA; if (gr > N_NODES - 1) gr = N_NODES - 1;
    const float* ap = A + (size_t)gr * HID + kc * 32;
    #pragma unroll
    for (int i = 0; i < 8; i++) {
        float4 v = ((const float4*)ap)[i];
        int kp = (kc * 32 + i * 4) >> 1;
        unsigned int p0 = (unsigned int)f2bf(v.x) | ((unsigned int)f2bf(v.y) << 16);
        unsigned int p1 = (unsigned int)f2bf(v.z) | ((unsigned int)f2bf(v.w) << 16);
        As2[kp * LDP + rowA] = p0;
        As2[(kp + 1) * LDP + rowA] = p1;
    }
    __syncthreads();
    const float* bp = Bs + j0;
    const float* ep = ((tc < 8) ? util0 + (size_t)m * HID * NH
                                : wtil0 + (size_t)m * HID * NH) + (tc & 7);
    #pragma unroll 2
    for (int kp = 0; kp < 64; kp++) {
        uint4 aa = *(const uint4*)&As2[kp * LDP + tr * 4];
        int k0 = kp * 2;
        float aev[4] = {bflo(aa.x), bflo(aa.y), bflo(aa.z), bflo(aa.w)};
        float aov[4] = {bfhi(aa.x), bfhi(aa.y), bfhi(aa.z), bfhi(aa.w)};
        float4 b00 = *(const float4*)&bp[(size_t)k0 * HID];
        float4 b01 = *(const float4*)&bp[(size_t)k0 * HID + 4];
        float4 b10 = *(const float4*)&bp[(size_t)(k0 + 1) * HID];
        float4 b11 = *(const float4*)&bp[(size_t)(k0 + 1) * HID + 4];
        float bv0[8] = {b00.x, b00.y, b00.z, b00.w, b01.x, b01.y, b01.z, b01.w};
        float bv1[8] = {b10.x, b10.y, b10.z, b10.w, b11.x, b11.y, b11.z, b11.w};
        float e0 = ep[(size_t)k0 * NH];
        float e1 = ep[(size_t)(k0 + 1) * NH];
        #pragma unroll
        for (int i = 0; i < 4; i++) {
            #pragma unroll
            for (int c = 0; c < 8; c++)
                acc[i][c] += aev[i] * bv0[c] + aov[i] * bv1[c];
            ae[i] += aev[i] * e0 + aov[i] * e1;
        }
    }
    #pragma unroll
    for (int i = 0; i < 4; i++) {
        int row = r0 + tr * 4 + i;
        if (row < N_NODES) {
            union { unsigned short us[8]; uint4 v; } pk;
            #pragma unroll
            for (int c = 0; c < 8; c++) pk.us[c] = f2bf(acc[i][c]);
            *(uint4*)&fs16[(size_t)row * HID + j0] = pk.v;
            if (tc < 8) el[row * NH + tc] = ae[i];
            else        er[row * NH + (tc - 8)] = ae[i];
        }
    }
}

// ---- K3: per-dst GAT aggregation, single pass, merged over m ----
__global__ __launch_bounds__(128) void k_gat(const int* __restrict__ ssrc0,
                                             const int* __restrict__ offs0,
                                             const float* __restrict__ el0,
                                             const float* __restrict__ er0,
                                             const unsigned short* __restrict__ fs0,
                                             float* __restrict__ z) {
    int m = blockIdx.y;
    const int* ssrc = ssrc0 + (size_t)m * NE;
    const int* offs = offs0 + (size_t)m * (N_NODES + 1);
    const float* el = el0 + (size_t)m * N_NODES * NH;
    const float* er = er0 + (size_t)m * N_NODES * NH;
    const unsigned short* fs16 = fs0 + (size_t)m * N_NODES * HID;
    int d = blockIdx.x;
    int j = threadIdx.x;
    int hh = j >> 4;
    int s0 = offs[d], s1 = offs[d + 1];
    float erd = er[d * NH + hh];
    float num = 0.f, den = 0.f;
    int i = s0;
    for (; i + 2 <= s1; i += 2) {
        int sa = ssrc[i], sb = ssrc[i + 1];
        float xa = el[sa * NH + hh] + erd;
        float xb = el[sb * NH + hh] + erd;
        unsigned short ua = fs16[(size_t)sa * HID + j];
        unsigned short ub = fs16[(size_t)sb * HID + j];
        xa = (xa >= 0.f) ? xa : NEG * xa;
        xb = (xb >= 0.f) ? xb : NEG * xb;
        float ea = __expf(xa), eb = __expf(xb);
        den += ea + eb;
        num += ea * bf2f(ua) + eb * bf2f(ub);
    }
    if (i < s1) {
        int s = ssrc[i];
        float x = el[s * NH + hh] + erd;
        x = (x >= 0.f) ? x : NEG * x;
        float e = __expf(x);
        den += e;
        num += e * bf2f(fs16[(size_t)s * HID + j]);
    }
    float val = num / fmaxf(den, 1e-9f);
    z[(size_t)(d * NM + m) * HID + j] = (val > 0.f) ? val : (__expf(val) - 1.f);
}

// -------- K4: w[r] = tanh(zel@W1 + b1) @ w2  (bf16 LDS A-tile) -------
__global__ __launch_bounds__(256) void k_semw(const float* __restrict__ A,
                                              const float* __restrict__ B,
                                              const float* __restrict__ b1,
                                              const float* __restrict__ ws2,
                                              float* __restrict__ w) {
    __shared__ unsigned int As2[64 * LDP];
    int tid = threadIdx.x;
    int tc = tid & 15, tr = tid >> 4;
    int r0 = blockIdx.x * 64;
    int j0 = tc * 8;
    int rowA = tid & 63;
    int kc = tid >> 6;
    float acc[4][8];
    #pragma unroll
    for (int i = 0; i < 4; i++)
        #pragma unroll
        for (int c = 0; c < 8; c++) acc[i][c] = 0.f;

    int gr = r0 + rowA; if (gr > NROWS - 1) gr = NROWS - 1;
    const float* ap = A + (size_t)gr * HID + kc * 32;
    #pragma unroll
    for (int i = 0; i < 8; i++) {
        float4 v = ((const float4*)ap)[i];
        int kp = (kc * 32 + i * 4) >> 1;
        unsigned int p0 = (unsigned int)f2bf(v.x) | ((unsigned int)f2bf(v.y) << 16);
        unsigned int p1 = (unsigned int)f2bf(v.z) | ((unsigned int)f2bf(v.w) << 16);
        As2[kp * LDP + rowA] = p0;
        As2[(kp + 1) * LDP + rowA] = p1;
    }
    __syncthreads();
    const float* bp = B + j0;
    #pragma unroll 2
    for (int kp = 0; kp < 64; kp++) {
        uint4 aa = *(const uint4*)&As2[kp * LDP + tr * 4];
        int k0 = kp * 2;
        float aev[4] = {bflo(aa.x), bflo(aa.y), bflo(aa.z), bflo(aa.w)};
        float aov[4] = {bfhi(aa.x), bfhi(aa.y), bfhi(aa.z), bfhi(aa.w)};
        float4 b00 = *(const float4*)&bp[(size_t)k0 * HID];
        float4 b01 = *(const float4*)&bp[(size_t)k0 * HID + 4];
        float4 b10 = *(const float4*)&bp[(size_t)(k0 + 1) * HID];
        float4 b11 = *(const float4*)&bp[(size_t)(k0 + 1) * HID + 4];
        float bv0[8] = {b00.x, b00.y, b00.z, b00.w, b01.x, b01.y, b01.z, b01.w};
        float bv1[8] = {b10.x, b10.y, b10.z, b10.w, b11.x, b11.y, b11.z, b11.w};
        #pragma unroll
        for (int i = 0; i < 4; i++)
            #pragma unroll
            for (int c = 0; c < 8; c++)
                acc[i][c] += aev[i] * bv0[c] + aov[i] * bv1[c];
    }
    float bb[8], s2[8];
    #pragma unroll
    for (int c = 0; c < 8; c++) { bb[c] = b1[j0 + c]; s2[c] = ws2[j0 + c]; }
    #pragma unroll
    for (int i = 0; i < 4; i++) {
        float v = 0.f;
        #pragma unroll
        for (int c = 0; c < 8; c++) v += tanhf(acc[i][c] + bb[c]) * s2[c];
        #pragma unroll
        for (int o = 8; o > 0; o >>= 1) v += __shfl_down(v, o, 16);
        int row = r0 + tr * 4 + i;
        if (tc == 0 && row < NROWS) w[row] = v;
    }
}

// ---------------- K5: beta softmax + fused + out ----------------
__global__ __launch_bounds__(256) void k_comb(const float* __restrict__ zel,
                                              const float* __restrict__ w,
                                              const float* __restrict__ Wout,
                                              const float* __restrict__ bout,
                                              float* __restrict__ out) {
    __shared__ float fusedL[2][HID];
    int half = threadIdx.x >> 7;
    int j = threadIdx.x & 127;
    int n = blockIdx.x * 2 + half;
    float w0 = w[n * NM + 0];
    float w1 = w[n * NM + 1];
    float w2 = w[n * NM + 2];
    float mx = fmaxf(w0, fmaxf(w1, w2));
    float e0 = __expf(w0 - mx);
    float e1 = __expf(w1 - mx);
    float e2 = __expf(w2 - mx);
    float inv = 1.f / (e0 + e1 + e2);
    size_t base = (size_t)n * NM * HID;
    float f = (e0 * zel[base + j] + e1 * zel[base + HID + j] + e2 * zel[base + 2 * HID + j]) * inv;
    fusedL[half][j] = f;
    __syncthreads();
    int c = j >> 4, t16 = j & 15;
    float p = 0.f;
    #pragma unroll
    for (int i = 0; i < 8; i++) {
        int jj = t16 + i * 16;
        p += fusedL[half][jj] * Wout[jj * NOUT + c];
    }
    #pragma unroll
    for (int o = 8; o > 0; o >>= 1) p += __shfl_down(p, o, 16);
    if (t16 == 0) out[n * NOUT + c] = p + bout[c];
}

extern "C" void kernel_launch(void* const* d_in, const int* in_sizes, int n_in,
                              void* d_out, int out_size, void* d_ws, size_t ws_size,
                              hipStream_t stream) {
    (void)in_sizes; (void)n_in; (void)out_size; (void)ws_size;
    const float* feat  = (const float*)d_in[0];
    const float* Wfc   = (const float*)d_in[1];
    const float* bfc   = (const float*)d_in[2];
    const float* Wsrc  = (const float*)d_in[3];
    const float* Wdst  = (const float*)d_in[4];
    const float* al    = (const float*)d_in[5];
    const float* ar    = (const float*)d_in[6];
    const float* Wsem1 = (const float*)d_in[7];
    const float* bsem1 = (const float*)d_in[8];
    const float* wsem2 = (const float*)d_in[9];
    const float* Wout  = (const float*)d_in[10];
    const float* bout  = (const float*)d_in[11];
    const int* srcI    = (const int*)d_in[12];
    const int* dstI    = (const int*)d_in[13];
    float* out = (float*)d_out;

    // fp32 section. h aliases the start of z: h is dead before k_gat writes z.
    float* z    = (float*)d_ws;                       // NROWS*HID
    float* h    = z;                                  // N_NODES*HID (alias)
    float* el   = z  + (size_t)NROWS * HID;           // NM*N_NODES*NH
    float* er   = el + (size_t)NM * N_NODES * NH;
    float* wsc  = er + (size_t)NM * N_NODES * NH;     // NROWS
    float* util = wsc + (size_t)NROWS;                // NM*HID*NH
    float* wtil = util + (size_t)NM * HID * NH;
    unsigned short* fs16 = (unsigned short*)(wtil + (size_t)NM * HID * NH); // NM*N_NODES*HID
    // int section
    int* deg    = (int*)(fs16 + (size_t)NM * N_NODES * HID);
    int* offs   = deg    + (size_t)NM * N_NODES;
    int* ssrc   = offs   + (size_t)NM * (N_NODES + 1);
    int* pfx    = ssrc   + (size_t)NM * NE;
    int* dstCur = pfx    + (size_t)NM * N_NODES;
    int* blksum = dstCur + (size_t)NM * N_NODES;
    int* blkbase= blksum + (size_t)NM * NBLK;
    int* binCur = blkbase+ (size_t)NM * NBLK;
    int2* pairs = (int2*)((((uintptr_t)(binCur + (size_t)NM * NBUCK)) + 15) & ~(uintptr_t)15);

    // ---- CSR build ----
    hipMemsetAsync(deg, 0, (size_t)NM * N_NODES * sizeof(int), stream);
    {
        dim3 ge((NE + 255) / 256, NM);
        dim3 gs(NBLK, NM);
        k_hist<<<ge, 256, 0, stream>>>(dstI, deg);
        k_scan1<<<gs, 256, 0, stream>>>(deg, pfx, blksum);
        k_scan2<<<NM, 256, 0, stream>>>(blksum, blkbase);
        k_scan3<<<gs, 256, 0, stream>>>(pfx, blkbase, offs, dstCur, binCur);
        for (int m = 0; m < NM; m++) {
            k_binA2<<<(NE + EPB - 1) / EPB, 256, 0, stream>>>(srcI + (size_t)m * NE,
                                                              dstI + (size_t)m * NE,
                                                              binCur + (size_t)m * NBUCK, pairs);
            k_binB<<<(NE + 255) / 256, 256, 0, stream>>>(pairs,
                                                         dstCur + (size_t)m * N_NODES,
                                                         ssrc + (size_t)m * NE);
        }
    }

    k_fc<<<(N_NODES + 63) / 64, 256, 0, stream>>>(feat, Wfc, bfc, h);
    k_attw<<<NM, 128, 0, stream>>>(Wsrc, Wdst, al, ar, util, wtil);

    {
        dim3 gp((N_NODES + 63) / 64, NM);
        k_proj<<<gp, 256, 0, stream>>>(h, Wsrc, util, wtil, fs16, el, er);
        dim3 gg(N_NODES, NM);
        k_gat<<<gg, 128, 0, stream>>>(ssrc, offs, el, er, fs16, z);
    }

    k_semw<<<(NROWS + 63) / 64, 256, 0, stream>>>(z, Wsem1, bsem1, wsem2, wsc);
    k_comb<<<N_NODES / 2, 256, 0, stream>>>(z, wsc, Wout, bout, out);
}